// Round 4
// baseline (43.970 us; speedup 1.0000x reference)
//
#include <hip/hip_runtime.h>
#include <math.h>

#define NPTS 4096
#define NB 8
#define EPSF 1e-12f
#define CCH 256             // candidates per chunk (R2-proven)
#define QPT 8               // queries per thread (R2-proven)
#define NCHUNK 16           // chunks per group
#define NGROUP 32           // (dir, b, qhalf)
#define GQ 2048             // queries per group

typedef float f32x2 __attribute__((ext_vector_type(2)));

// d = {fma(a.lo, b.lo, c.lo), fma(a.hi, b.lo, c.lo)}  (b word0, c word0 broadcast)
static __device__ __forceinline__ f32x2 pk_fma_bx(f32x2 a, f32x2 b, f32x2 c){
    f32x2 d;
    asm("v_pk_fma_f32 %0, %1, %2, %3 op_sel:[0,0,0] op_sel_hi:[1,0,0]"
        : "=v"(d) : "v"(a), "v"(b), "v"(c));
    return d;
}
// d = {fma(a.lo, b.hi, c.lo), fma(a.hi, b.hi, c.hi)}  (b word1 broadcast, c packed)
static __device__ __forceinline__ f32x2 pk_fma_by(f32x2 a, f32x2 b, f32x2 c){
    f32x2 d;
    asm("v_pk_fma_f32 %0, %1, %2, %3 op_sel:[0,1,0] op_sel_hi:[1,1,1]"
        : "=v"(d) : "v"(a), "v"(b), "v"(c));
    return d;
}
static __device__ __forceinline__ float fmin3(float a, float b, float c){
    float d;
    asm("v_min3_f32 %0, %1, %2, %3" : "=v"(d) : "v"(a), "v"(b), "v"(c));
    return d;
}

static __device__ __forceinline__ void project_pt(const float* __restrict__ p3,
                                                  const float* __restrict__ Pb,
                                                  float& ix, float& iy){
    float x = p3[0], y = p3[1], z = p3[2];
    float px = fmaf(Pb[0],x, fmaf(Pb[1],y, fmaf(Pb[2],z,  Pb[3])));
    float py = fmaf(Pb[4],x, fmaf(Pb[5],y, fmaf(Pb[6],z,  Pb[7])));
    float pz = fmaf(Pb[8],x, fmaf(Pb[9],y, fmaf(Pb[10],z, Pb[11])));
    ix = px / pz;
    iy = py / pz;
}

// 512 blocks = 32 groups (dir,b,qhalf) x 16 candidate chunks.
// Phase 1 (all blocks): project queries+candidates, chunk-min, store to
//   minpart[group][chunk][2048] (group-contiguous).
// Phase 2 (last block of each group): min across 16 chunks + sqrt + block sum.
// Phase 3 (last of the 32 reducers): fixed-order final sum -> out.
__global__ __launch_bounds__(256) void chamfer_mega(
        const float* __restrict__ pred, const float* __restrict__ gt,
        const float* __restrict__ P, float* __restrict__ minpart,
        unsigned* __restrict__ cnt, float* __restrict__ partials,
        float* __restrict__ out){
    __shared__ float4 cand[CCH];   // {-2x, -2y, |c|^2, 0}
    __shared__ float sm[256];
    __shared__ int flag;
    int bid   = blockIdx.x;
    int chunk = bid & 15;
    int qhalf = (bid >> 4) & 1;
    int b     = (bid >> 5) & 7;
    int dir   = (bid >> 8) & 1;
    int g     = bid >> 4;          // 0..31
    int t = threadIdx.x;

    const float* Pb   = P + b * 12;
    const float* qsrc = dir ? pred : gt;
    const float* csrc = dir ? gt : pred;

    // ---- Phase 1: chamfer (R2-proven geometry) ----
    {
        const float* p3 = csrc + (size_t)(b*NPTS + chunk*CCH + t) * 3;
        float cx, cy; project_pt(p3, Pb, cx, cy);
        cand[t] = make_float4(-2.0f*cx, -2.0f*cy, fmaf(cx,cx, cy*cy), 0.0f);
    }

    f32x2 axp[QPT/2], ayp[QPT/2];
    float a2[QPT];
    #pragma unroll
    for (int q = 0; q < QPT; ++q){
        int qi = qhalf*GQ + q*256 + t;
        const float* p3 = qsrc + (size_t)(b*NPTS + qi) * 3;
        float ix, iy; project_pt(p3, Pb, ix, iy);
        axp[q>>1][q&1] = ix;
        ayp[q>>1][q&1] = iy;
        a2[q] = fmaf(ix,ix, iy*iy);
    }
    float mn[QPT];
    #pragma unroll
    for (int q = 0; q < QPT; ++q) mn[q] = 3.4e38f;

    __syncthreads();

    #pragma unroll 4
    for (int ci = 0; ci < CCH; ci += 2){
        float4 cd0 = cand[ci];
        float4 cd1 = cand[ci+1];
        f32x2 c0lo = {cd0.x, cd0.y}, c0hi = {cd0.z, cd0.w};
        f32x2 c1lo = {cd1.x, cd1.y}, c1hi = {cd1.z, cd1.w};
        #pragma unroll
        for (int p = 0; p < QPT/2; ++p){
            f32x2 t0 = pk_fma_bx(axp[p], c0lo, c0hi);
            t0 = pk_fma_by(ayp[p], c0lo, t0);
            f32x2 t1 = pk_fma_bx(axp[p], c1lo, c1hi);
            t1 = pk_fma_by(ayp[p], c1lo, t1);
            mn[2*p]   = fmin3(t0.x, t1.x, mn[2*p]);
            mn[2*p+1] = fmin3(t0.y, t1.y, mn[2*p+1]);
        }
    }

    float* gp = minpart + (size_t)g * (NCHUNK*GQ);
    #pragma unroll
    for (int q = 0; q < QPT; ++q){
        gp[chunk*GQ + q*256 + t] = mn[q] + a2[q];
    }

    // drain this block's stores to L2, then arrive (release pushes past XCD L2)
    __syncthreads();
    if (t == 0){
        unsigned prev = __hip_atomic_fetch_add(&cnt[g], 1u,
                            __ATOMIC_ACQ_REL, __HIP_MEMORY_SCOPE_AGENT);
        flag = (prev == NCHUNK-1);
    }
    __syncthreads();
    if (!flag) return;

    // ---- Phase 2: group reduce (one block per group) ----
    {
        const float* gq0 = gp + t*8;
        float4 m0 = *(const float4*)(gq0);
        float4 m1 = *(const float4*)(gq0 + 4);
        #pragma unroll
        for (int c = 1; c < NCHUNK; ++c){
            float4 v0 = *(const float4*)(gq0 + c*GQ);
            float4 v1 = *(const float4*)(gq0 + c*GQ + 4);
            m0.x = fminf(m0.x, v0.x); m0.y = fminf(m0.y, v0.y);
            m0.z = fminf(m0.z, v0.z); m0.w = fminf(m0.w, v0.w);
            m1.x = fminf(m1.x, v1.x); m1.y = fminf(m1.y, v1.y);
            m1.z = fminf(m1.z, v1.z); m1.w = fminf(m1.w, v1.w);
        }
        float s = sqrtf(fmaxf(m0.x, EPSF)) + sqrtf(fmaxf(m0.y, EPSF))
                + sqrtf(fmaxf(m0.z, EPSF)) + sqrtf(fmaxf(m0.w, EPSF))
                + sqrtf(fmaxf(m1.x, EPSF)) + sqrtf(fmaxf(m1.y, EPSF))
                + sqrtf(fmaxf(m1.z, EPSF)) + sqrtf(fmaxf(m1.w, EPSF));
        sm[t] = s;
    }
    __syncthreads();
    #pragma unroll
    for (int o = 128; o > 0; o >>= 1){
        if (t < o) sm[t] += sm[t + o];
        __syncthreads();
    }
    if (t == 0){
        __hip_atomic_store(&partials[g], sm[0],
                           __ATOMIC_RELEASE, __HIP_MEMORY_SCOPE_AGENT);
        unsigned p2 = __hip_atomic_fetch_add(&cnt[NGROUP], 1u,
                           __ATOMIC_ACQ_REL, __HIP_MEMORY_SCOPE_AGENT);
        flag = (p2 == NGROUP-1);
    }
    __syncthreads();
    if (!flag) return;

    // ---- Phase 3: final fixed-order sum (one block) ----
    if (t < NGROUP){
        sm[t] = __hip_atomic_load(&partials[t],
                    __ATOMIC_ACQUIRE, __HIP_MEMORY_SCOPE_AGENT);
    }
    __syncthreads();
    if (t == 0){
        float s = 0.0f;
        #pragma unroll
        for (int i = 0; i < NGROUP; ++i) s += sm[i];
        out[0] = s * (1.0f / 32768.0f);
    }
}

extern "C" void kernel_launch(void* const* d_in, const int* in_sizes, int n_in,
                              void* d_out, int out_size, void* d_ws, size_t ws_size,
                              hipStream_t stream) {
    const float* pred = (const float*)d_in[0];
    const float* gt   = (const float*)d_in[1];
    const float* P    = (const float*)d_in[2];
    float* out = (float*)d_out;

    const size_t MINPART_BYTES = (size_t)NGROUP * NCHUNK * GQ * 4;   // 4 MB
    float*    minpart  = (float*)d_ws;
    unsigned* cnt      = (unsigned*)((char*)d_ws + MINPART_BYTES);   // 33 counters
    float*    partials = (float*)((char*)d_ws + MINPART_BYTES + 256);

    hipMemsetAsync(cnt, 0, 256, stream);   // zero counters every replay
    chamfer_mega<<<512, 256, 0, stream>>>(pred, gt, P, minpart, cnt, partials, out);
}

// Round 5
// 27.743 us; speedup vs baseline: 1.5849x; 1.5849x over previous
//
#include <hip/hip_runtime.h>
#include <math.h>

#define NPTS 4096
#define NB 8
#define NQTOT (2*NB*NPTS)   // 65536 query slots (both directions)
#define EPSF 1e-12f
#define NCHUNK 16
#define CCH 256             // candidates per chunk (proven)
#define QPT 4               // queries per thread (R5: occupancy 4 blocks/CU)

typedef float f32x2 __attribute__((ext_vector_type(2)));

// d = {fma(a.lo, b.lo, c.lo), fma(a.hi, b.lo, c.lo)}  (b word0, c word0 broadcast)
static __device__ __forceinline__ f32x2 pk_fma_bx(f32x2 a, f32x2 b, f32x2 c){
    f32x2 d;
    asm("v_pk_fma_f32 %0, %1, %2, %3 op_sel:[0,0,0] op_sel_hi:[1,0,0]"
        : "=v"(d) : "v"(a), "v"(b), "v"(c));
    return d;
}
// d = {fma(a.lo, b.hi, c.lo), fma(a.hi, b.hi, c.hi)}  (b word1 broadcast, c packed)
static __device__ __forceinline__ f32x2 pk_fma_by(f32x2 a, f32x2 b, f32x2 c){
    f32x2 d;
    asm("v_pk_fma_f32 %0, %1, %2, %3 op_sel:[0,1,0] op_sel_hi:[1,1,1]"
        : "=v"(d) : "v"(a), "v"(b), "v"(c));
    return d;
}
static __device__ __forceinline__ float fmin3(float a, float b, float c){
    float d;
    asm("v_min3_f32 %0, %1, %2, %3" : "=v"(d) : "v"(a), "v"(b), "v"(c));
    return d;
}

static __device__ __forceinline__ void project_pt(const float* __restrict__ p3,
                                                  const float* __restrict__ Pb,
                                                  float& ix, float& iy){
    float x = p3[0], y = p3[1], z = p3[2];
    float px = fmaf(Pb[0],x, fmaf(Pb[1],y, fmaf(Pb[2],z,  Pb[3])));
    float py = fmaf(Pb[4],x, fmaf(Pb[5],y, fmaf(Pb[6],z,  Pb[7])));
    float pz = fmaf(Pb[8],x, fmaf(Pb[9],y, fmaf(Pb[10],z, Pb[11])));
    ix = px / pz;
    iy = py / pz;
}

// 1024 blocks = 2 dirs x 8 batches x 4 query-quarters x 16 candidate chunks.
// Each block: project its 256 candidates + 1024 queries (4/thread), min of
// t = |c|^2 - 2 a.c over the chunk, store d2 = min_t + |a|^2 to
// minpart[chunk][global_query]. No atomics; kernel boundary provides coherence.
__global__ __launch_bounds__(256) void chamfer_fused(
        const float* __restrict__ pred, const float* __restrict__ gt,
        const float* __restrict__ P, float* __restrict__ minpart){
    __shared__ float4 cand[CCH];   // {-2x, -2y, |c|^2, 0}
    int bid   = blockIdx.x;
    int chunk = bid & 15;
    int qq    = (bid >> 4) & 3;
    int b     = (bid >> 6) & 7;
    int dir   = (bid >> 9) & 1;
    int t = threadIdx.x;

    const float* Pb   = P + b * 12;
    const float* qsrc = dir ? pred : gt;
    const float* csrc = dir ? gt : pred;

    // project this block's candidate chunk into LDS
    {
        const float* p3 = csrc + (size_t)(b*NPTS + chunk*CCH + t) * 3;
        float cx, cy; project_pt(p3, Pb, cx, cy);
        cand[t] = make_float4(-2.0f*cx, -2.0f*cy, fmaf(cx,cx, cy*cy), 0.0f);
    }

    // project this thread's 4 queries (packed in pairs for pk_fma)
    f32x2 axp[QPT/2], ayp[QPT/2];
    float a2[QPT];
    #pragma unroll
    for (int q = 0; q < QPT; ++q){
        int qi = qq*1024 + q*256 + t;
        const float* p3 = qsrc + (size_t)(b*NPTS + qi) * 3;
        float ix, iy; project_pt(p3, Pb, ix, iy);
        axp[q>>1][q&1] = ix;
        ayp[q>>1][q&1] = iy;
        a2[q] = fmaf(ix,ix, iy*iy);
    }
    float mn[QPT];
    #pragma unroll
    for (int q = 0; q < QPT; ++q) mn[q] = 3.4e38f;

    __syncthreads();

    #pragma unroll 4
    for (int ci = 0; ci < CCH; ci += 2){
        float4 cd0 = cand[ci];
        float4 cd1 = cand[ci+1];
        f32x2 c0lo = {cd0.x, cd0.y}, c0hi = {cd0.z, cd0.w};
        f32x2 c1lo = {cd1.x, cd1.y}, c1hi = {cd1.z, cd1.w};
        #pragma unroll
        for (int p = 0; p < QPT/2; ++p){
            f32x2 t0 = pk_fma_bx(axp[p], c0lo, c0hi);
            t0 = pk_fma_by(ayp[p], c0lo, t0);
            f32x2 t1 = pk_fma_bx(axp[p], c1lo, c1hi);
            t1 = pk_fma_by(ayp[p], c1lo, t1);
            mn[2*p]   = fmin3(t0.x, t1.x, mn[2*p]);
            mn[2*p+1] = fmin3(t0.y, t1.y, mn[2*p+1]);
        }
    }

    int gq = dir*(NB*NPTS) + b*NPTS + qq*1024 + t;
    #pragma unroll
    for (int q = 0; q < QPT; ++q){
        minpart[(size_t)chunk*NQTOT + gq + q*256] = mn[q] + a2[q];
    }
}

// 16-way min across chunks, sqrt, per-block partial sum.
__global__ __launch_bounds__(256) void reduce_min_sum(
        const float* __restrict__ minpart, float* __restrict__ partials){
    __shared__ float sm[256];
    int t = threadIdx.x;
    int i = blockIdx.x * 256 + t;   // 256 blocks cover 65536 queries
    float m0 = minpart[i];
    #pragma unroll
    for (int c = 1; c < NCHUNK; ++c) m0 = fminf(m0, minpart[(size_t)c*NQTOT + i]);
    float s = sqrtf(fmaxf(m0, EPSF));
    sm[t] = s; __syncthreads();
    #pragma unroll
    for (int o = 128; o > 0; o >>= 1){
        if (t < o) sm[t] += sm[t + o];
        __syncthreads();
    }
    if (t == 0) partials[blockIdx.x] = sm[0];
}

__global__ void reduce_final(const float* __restrict__ partials,
                             float* __restrict__ out){
    __shared__ float sm[256];
    int t = threadIdx.x;
    sm[t] = partials[t];
    __syncthreads();
    #pragma unroll
    for (int o = 128; o > 0; o >>= 1){
        if (t < o) sm[t] += sm[t + o];
        __syncthreads();
    }
    if (t == 0) out[0] = sm[0] * (1.0f / 32768.0f);
}

extern "C" void kernel_launch(void* const* d_in, const int* in_sizes, int n_in,
                              void* d_out, int out_size, void* d_ws, size_t ws_size,
                              hipStream_t stream) {
    const float* pred = (const float*)d_in[0];
    const float* gt   = (const float*)d_in[1];
    const float* P    = (const float*)d_in[2];
    float* out = (float*)d_out;

    float* minpart  = (float*)d_ws;                                        // 4 MB
    float* partials = (float*)((char*)d_ws + (size_t)NCHUNK*NQTOT*4);      // 1 KB

    chamfer_fused<<<1024, 256, 0, stream>>>(pred, gt, P, minpart);
    reduce_min_sum<<<256, 256, 0, stream>>>(minpart, partials);
    reduce_final<<<1, 256, 0, stream>>>(partials, out);
}